// Round 7
// baseline (244.189 us; speedup 1.0000x reference)
//
#include <hip/hip_runtime.h>

#define ROWS 4096
#define NCOL 8192
#define THREADS 256
#define WAVES (THREADS / 64)        // 4
#define F4PT (NCOL / (THREADS * 4)) // 8 float4 per thread
#define CAP 256                     // candidate list capacity

// ---------------- Kernel 1: tau per row (read-only scan + tiny solve) ----------------
__global__ __launch_bounds__(THREADS, 8)
void tau_kernel(const float* __restrict__ x, float* __restrict__ tau) {
    const int row  = blockIdx.x;
    const int tid  = threadIdx.x;
    const int wave = tid >> 6;
    const int lane = tid & 63;
    const size_t base = (size_t)row * NCOL;
    const float4* __restrict__ xr = (const float4*)(x + base);

    __shared__ float swm[WAVES];   // wave max
    __shared__ float swe[WAVES];   // wave evicted-max
    __shared__ float cand[CAP];
    __shared__ int   scnt;
    __shared__ float swv[WAVES];   // fallback partial sum
    __shared__ int   swk[WAVES];   // fallback partial count

    if (tid == 0) scnt = 0;

    // ---- Single streaming scan: online per-thread top-4 + evicted max ----
    float c0 = -INFINITY, c1 = -INFINITY, c2 = -INFINITY, c3 = -INFINITY;
    float e  = -INFINITY;

#define INS(qv) do {                                    \
        float n = (qv), mx;                             \
        mx = fmaxf(c0, n); n = fminf(c0, n); c0 = mx;   \
        mx = fmaxf(c1, n); n = fminf(c1, n); c1 = mx;   \
        mx = fmaxf(c2, n); n = fminf(c2, n); c2 = mx;   \
        mx = fmaxf(c3, n); n = fminf(c3, n); c3 = mx;   \
        e = fmaxf(e, n);                                \
    } while (0)

#pragma unroll
    for (int j = 0; j < F4PT; ++j) {
        float4 q = xr[tid + THREADS * j];
        INS(q.x); INS(q.y); INS(q.z); INS(q.w);
    }
#undef INS

    // ---- Block max + evicted-max ----
    float m = c0, ew = e;
#pragma unroll
    for (int off = 32; off > 0; off >>= 1) {
        m  = fmaxf(m,  __shfl_xor(m,  off, 64));
        ew = fmaxf(ew, __shfl_xor(ew, off, 64));
    }
    if (lane == 0) { swm[wave] = m; swe[wave] = ew; }
    __syncthreads();                                   // (1)
    float bm = swm[0], be = swe[0];
#pragma unroll
    for (int w = 1; w < WAVES; ++w) { bm = fmaxf(bm, swm[w]); be = fmaxf(be, swe[w]); }
    const float t0 = bm - 1.0f;   // tau* >= max-1

    // ---- Candidates above t0 from each thread's top-4 (expected ~21 total) ----
    if (c0 > t0) { int p = atomicAdd(&scnt, 1); if (p < CAP) cand[p] = c0; }
    if (c1 > t0) { int p = atomicAdd(&scnt, 1); if (p < CAP) cand[p] = c1; }
    if (c2 > t0) { int p = atomicAdd(&scnt, 1); if (p < CAP) cand[p] = c2; }
    if (c3 > t0) { int p = atomicAdd(&scnt, 1); if (p < CAP) cand[p] = c3; }
    __syncthreads();                                   // (2)

    const int k0 = scnt;
    float t = t0;
    bool need_full = (k0 > CAP);

    if (!need_full) {
        // Wave-redundant, shuffle-only Michelot on the tiny list (identical in all waves).
        const float q0 = (lane       < k0) ? cand[lane      ] : -INFINITY;
        const float q1 = (lane + 64  < k0) ? cand[lane + 64 ] : -INFINITY;
        const float q2 = (lane + 128 < k0) ? cand[lane + 128] : -INFINITY;
        const float q3 = (lane + 192 < k0) ? cand[lane + 192] : -INFINITY;
        int prev_k = -1;
        for (int it = 0; it < 64; ++it) {
            float s = 0.0f; int k = 0;
            if (q0 > t) { s += q0; ++k; }
            if (q1 > t) { s += q1; ++k; }
            if (q2 > t) { s += q2; ++k; }
            if (q3 > t) { s += q3; ++k; }
#pragma unroll
            for (int off = 32; off > 0; off >>= 1) {
                s += __shfl_xor(s, off, 64);
                k += __shfl_xor(k, off, 64);
            }
            if (k == prev_k) break;        // support stable => fixed point
            prev_k = k;
            t = (s - 1.0f) / (float)k;
        }
        need_full = (be > t);              // evicted value above tau => must rescan
    }

    if (need_full) {
        // ---- Exact fallback (cold): block-wide Michelot, row re-read from cache ----
        int prev_k = -1;
        for (int it = 0; it < 200; ++it) {
            float s = 0.0f; int k = 0;
#pragma unroll
            for (int j = 0; j < F4PT; ++j) {
                float4 q = xr[tid + THREADS * j];
                if (q.x > t) { s += q.x; ++k; }
                if (q.y > t) { s += q.y; ++k; }
                if (q.z > t) { s += q.z; ++k; }
                if (q.w > t) { s += q.w; ++k; }
            }
#pragma unroll
            for (int off = 32; off > 0; off >>= 1) {
                s += __shfl_xor(s, off, 64);
                k += __shfl_xor(k, off, 64);
            }
            if (lane == 0) { swv[wave] = s; swk[wave] = k; }
            __syncthreads();
            float st = 0.0f; int kt = 0;
#pragma unroll
            for (int w = 0; w < WAVES; ++w) { st += swv[w]; kt += swk[w]; }
            __syncthreads();
            if (kt == prev_k) break;       // block-uniform decision
            prev_k = kt;
            t = (st - 1.0f) / (float)kt;
        }
    }

    if (tid == 0) tau[row] = t;
}

// ---------------- Kernel 2: pure streaming epilogue (m13 copy pattern) ----------------
#define K2_THREADS 256
#define K2_BLOCKS  2048
#define TOTAL_F4   (ROWS * (size_t)NCOL / 4)          // 8388608
#define K2_STRIDE  ((size_t)K2_BLOCKS * K2_THREADS)   // 524288
#define K2_ITERS   (TOTAL_F4 / K2_STRIDE)             // 16

__global__ __launch_bounds__(K2_THREADS, 8)
void epilogue_kernel(const float* __restrict__ x, const float* __restrict__ tau,
                     float* __restrict__ out) {
    const size_t i0 = (size_t)blockIdx.x * K2_THREADS + threadIdx.x;
    const float4* __restrict__ xr  = (const float4*)x;
    float4* __restrict__ outr      = (float4*)out;

#pragma unroll 4
    for (int k = 0; k < (int)K2_ITERS; ++k) {
        const size_t i = i0 + (size_t)k * K2_STRIDE;
        const float tt = tau[i >> 11];     // 2048 float4 per row; wave-uniform, L1-hot
        float4 q = xr[i];
        float4 r;
        r.x = fmaxf(q.x - tt, 0.0f);
        r.y = fmaxf(q.y - tt, 0.0f);
        r.z = fmaxf(q.z - tt, 0.0f);
        r.w = fmaxf(q.w - tt, 0.0f);
        outr[i] = r;
    }
}

extern "C" void kernel_launch(void* const* d_in, const int* in_sizes, int n_in,
                              void* d_out, int out_size, void* d_ws, size_t ws_size,
                              hipStream_t stream) {
    const float* x = (const float*)d_in[0];
    float* out = (float*)d_out;
    float* tau = (float*)d_ws;             // 4096 * 4 B = 16 KiB workspace

    tau_kernel<<<ROWS, THREADS, 0, stream>>>(x, tau);
    epilogue_kernel<<<K2_BLOCKS, K2_THREADS, 0, stream>>>(x, tau, out);
}

// Round 8
// 242.889 us; speedup vs baseline: 1.0053x; 1.0053x over previous
//
#include <hip/hip_runtime.h>

#define ROWS 4096
#define NCOL 8192
#define THREADS 256
#define WAVES (THREADS / 64)        // 4
#define F4PT (NCOL / (THREADS * 4)) // 8 float4 per thread
#define CAP 256                     // candidate list capacity

// ---------------- Kernel A: pure write-stream zero fill --------------------
// Structure-identical to the runtime's fillBufferAligned measured at 6.6 TB/s.
#define ZB 2048
#define ZSTRIDE ((size_t)ZB * THREADS)                 // 524288 float4 per sweep
#define ZITERS  ((ROWS * (size_t)NCOL / 4) / ZSTRIDE)  // 16

__global__ __launch_bounds__(THREADS, 8)
void zero_kernel(float* __restrict__ out) {
    float4* __restrict__ o = (float4*)out;
    const size_t i0 = (size_t)blockIdx.x * THREADS + threadIdx.x;
    const float4 z = make_float4(0.0f, 0.0f, 0.0f, 0.0f);
#pragma unroll 4
    for (int k = 0; k < (int)ZITERS; ++k)
        o[i0 + (size_t)k * ZSTRIDE] = z;
}

// ---------------- Kernel B: read-only scan -> tau -> sparse scatter --------
__global__ __launch_bounds__(THREADS, 8)
void tau_scatter_kernel(const float* __restrict__ x, float* __restrict__ out) {
    const int row  = blockIdx.x;
    const int tid  = threadIdx.x;
    const int wave = tid >> 6;
    const int lane = tid & 63;
    const size_t base = (size_t)row * NCOL;
    const float4* __restrict__ xr = (const float4*)(x + base);

    __shared__ float swm[WAVES];   // wave max
    __shared__ float swe[WAVES];   // wave evicted-max
    __shared__ float cand[CAP];
    __shared__ int   scnt;
    __shared__ float swv[WAVES];   // fallback partial sum
    __shared__ int   swk[WAVES];   // fallback partial count

    if (tid == 0) scnt = 0;

    // ---- All 8 loads issued before any use: 8-deep MLP per thread ----
    const float4 q0 = xr[tid];
    const float4 q1 = xr[tid + THREADS];
    const float4 q2 = xr[tid + THREADS * 2];
    const float4 q3 = xr[tid + THREADS * 3];
    const float4 q4 = xr[tid + THREADS * 4];
    const float4 q5 = xr[tid + THREADS * 5];
    const float4 q6 = xr[tid + THREADS * 6];
    const float4 q7 = xr[tid + THREADS * 7];

    // ---- Online per-thread top-4 + evicted max ----
    float c0 = -INFINITY, c1 = -INFINITY, c2 = -INFINITY, c3 = -INFINITY;
    float e  = -INFINITY;
#define INS(qv) do {                                    \
        float n = (qv), mx;                             \
        mx = fmaxf(c0, n); n = fminf(c0, n); c0 = mx;   \
        mx = fmaxf(c1, n); n = fminf(c1, n); c1 = mx;   \
        mx = fmaxf(c2, n); n = fminf(c2, n); c2 = mx;   \
        mx = fmaxf(c3, n); n = fminf(c3, n); c3 = mx;   \
        e = fmaxf(e, n);                                \
    } while (0)
#define INS4(q) do { INS(q.x); INS(q.y); INS(q.z); INS(q.w); } while (0)
    INS4(q0); INS4(q1); INS4(q2); INS4(q3);
    INS4(q4); INS4(q5); INS4(q6); INS4(q7);
#undef INS4
#undef INS

    // ---- Block max + evicted-max ----
    float m = c0, ew = e;
#pragma unroll
    for (int off = 32; off > 0; off >>= 1) {
        m  = fmaxf(m,  __shfl_xor(m,  off, 64));
        ew = fmaxf(ew, __shfl_xor(ew, off, 64));
    }
    if (lane == 0) { swm[wave] = m; swe[wave] = ew; }
    __syncthreads();                                   // (1)
    float bm = swm[0], be = swe[0];
#pragma unroll
    for (int w = 1; w < WAVES; ++w) { bm = fmaxf(bm, swm[w]); be = fmaxf(be, swe[w]); }
    const float t0 = bm - 1.0f;   // tau* >= max-1

    // ---- Candidates above t0 from per-thread top-4 (expected ~21 total) ----
    if (c0 > t0) { int p = atomicAdd(&scnt, 1); if (p < CAP) cand[p] = c0; }
    if (c1 > t0) { int p = atomicAdd(&scnt, 1); if (p < CAP) cand[p] = c1; }
    if (c2 > t0) { int p = atomicAdd(&scnt, 1); if (p < CAP) cand[p] = c2; }
    if (c3 > t0) { int p = atomicAdd(&scnt, 1); if (p < CAP) cand[p] = c3; }
    __syncthreads();                                   // (2)

    const int k0 = scnt;
    float t = t0;
    bool need_full = (k0 > CAP);

    if (!need_full) {
        // Wave-redundant shuffle-only Michelot on the tiny list.
        const float p0 = (lane       < k0) ? cand[lane      ] : -INFINITY;
        const float p1 = (lane + 64  < k0) ? cand[lane + 64 ] : -INFINITY;
        const float p2 = (lane + 128 < k0) ? cand[lane + 128] : -INFINITY;
        const float p3 = (lane + 192 < k0) ? cand[lane + 192] : -INFINITY;
        int prev_k = -1;
        for (int it = 0; it < 64; ++it) {
            float s = 0.0f; int k = 0;
            if (p0 > t) { s += p0; ++k; }
            if (p1 > t) { s += p1; ++k; }
            if (p2 > t) { s += p2; ++k; }
            if (p3 > t) { s += p3; ++k; }
#pragma unroll
            for (int off = 32; off > 0; off >>= 1) {
                s += __shfl_xor(s, off, 64);
                k += __shfl_xor(k, off, 64);
            }
            if (k == prev_k) break;        // support stable => fixed point
            prev_k = k;
            t = (s - 1.0f) / (float)k;
        }
        need_full = (be > t);              // evicted value above tau => rescan
    }

    if (need_full) {
        // ---- Exact fallback (cold): block-wide Michelot on cache-hot row ----
        int prev_k = -1;
        for (int it = 0; it < 200; ++it) {
            float s = 0.0f; int k = 0;
#pragma unroll
            for (int j = 0; j < F4PT; ++j) {
                float4 q = xr[tid + THREADS * j];
                if (q.x > t) { s += q.x; ++k; }
                if (q.y > t) { s += q.y; ++k; }
                if (q.z > t) { s += q.z; ++k; }
                if (q.w > t) { s += q.w; ++k; }
            }
#pragma unroll
            for (int off = 32; off > 0; off >>= 1) {
                s += __shfl_xor(s, off, 64);
                k += __shfl_xor(k, off, 64);
            }
            if (lane == 0) { swv[wave] = s; swk[wave] = k; }
            __syncthreads();
            float st = 0.0f; int kt = 0;
#pragma unroll
            for (int w = 0; w < WAVES; ++w) { st += swv[w]; kt += swk[w]; }
            __syncthreads();
            if (kt == prev_k) break;       // block-uniform decision
            prev_k = kt;
            t = (st - 1.0f) / (float)kt;
        }
    }

    // ---- Sparse scatter: only elements above tau (expected ~5/row). ----
    // Row is L1/L2-hot (this block just streamed it). out is pre-zeroed.
#pragma unroll
    for (int j = 0; j < F4PT; ++j) {
        float4 q = xr[tid + THREADS * j];
        const size_t col = ((size_t)tid + THREADS * j) * 4;
        if (q.x > t) out[base + col    ] = q.x - t;
        if (q.y > t) out[base + col + 1] = q.y - t;
        if (q.z > t) out[base + col + 2] = q.z - t;
        if (q.w > t) out[base + col + 3] = q.w - t;
    }
}

extern "C" void kernel_launch(void* const* d_in, const int* in_sizes, int n_in,
                              void* d_out, int out_size, void* d_ws, size_t ws_size,
                              hipStream_t stream) {
    const float* x = (const float*)d_in[0];
    float* out = (float*)d_out;

    zero_kernel<<<ZB, THREADS, 0, stream>>>(out);
    tau_scatter_kernel<<<ROWS, THREADS, 0, stream>>>(x, out);
}